// Round 7
// baseline (338.523 us; speedup 1.0000x reference)
//
#include <hip/hip_runtime.h>
#include <hip/hip_bf16.h>

// ---------------------------------------------------------------------------
// FCx2DetHead pipeline. R7 changes (R6: 2-barrier K-loop drain = ~2400 cyc
// per 64-cyc k-step; traffic already optimal at 82 MB):
//  - GEMM with NO LDS and NO barriers: MFMA A/B fragments loaded directly
//    from global (NT layout makes the fragment pattern a contiguous 16B/lane
//    load). B fp32 -> f2bf in-reg. 8 loads : 8 MFMA per k-step, manual
//    1-step prefetch -> compiler emits fine-grained vmcnt (no vmcnt(0)
//    drain since no __syncthreads). Waves fully independent.
// ---------------------------------------------------------------------------

#define NROI 256
#define NB   8
#define INF  12544   // 256*49
#define DFC  1024
#define FCC  512

typedef __attribute__((ext_vector_type(8))) short short8;
typedef __attribute__((ext_vector_type(4))) float floatx4;

static __device__ __forceinline__ unsigned short f2bf(float f) {
    unsigned int u = __float_as_uint(f);
    unsigned int r = (u + 0x7fffu + ((u >> 16) & 1u)) >> 16;
    return (unsigned short)r;
}

// ---------------- transpose x (B,C,H,W) -> feat (B,H,W,C) -------------------
__global__ __launch_bounds__(256) void transpose_kernel(
        const float* __restrict__ x, float* __restrict__ xT) {
    __shared__ float t[32][33];
    int b  = blockIdx.z;
    int cb = blockIdx.y * 32;     // channel tile
    int lb = blockIdx.x * 32;     // hw tile (0..624)
    int tx = threadIdx.x & 31, ty = threadIdx.x >> 5;
#pragma unroll
    for (int r = 0; r < 4; ++r) {
        int c = cb + ty + r * 8, l = lb + tx;
        if (l < 625) t[ty + r * 8][tx] = x[(size_t)(b * 256 + c) * 625 + l];
    }
    __syncthreads();
#pragma unroll
    for (int r = 0; r < 4; ++r) {
        int l = lb + ty + r * 8, c = cb + tx;
        if (l < 625) xT[((size_t)b * 625 + l) * 256 + c] = t[tx][ty + r * 8];
    }
}

// ---------------- pool prep: per (roi,bin) 16-cell weight grid --------------
__global__ __launch_bounds__(256) void pool_prep(
        const float* __restrict__ rois, const float* __restrict__ off, int has_off,
        float* __restrict__ wbuf, int* __restrict__ bbuf) {
    __shared__ float g[256][16];
    const float SSC = (float)(25.0 / 255.0);
    int tid = threadIdx.x;
    int idx = blockIdx.x * 256 + tid;          // [0, 12544)
    int n = idx / 49;
    int bin = idx - n * 49;
    const float* r = rois + n * 5;
    int b = (int)r[0];
    float sw = rintf(r[1]) * SSC - 0.5f;
    float sh = rintf(r[2]) * SSC - 0.5f;
    float rw = fmaxf((rintf(r[3]) + 1.0f) * SSC - 0.5f - sw, 0.1f);
    float rh = fmaxf((rintf(r[4]) + 1.0f) * SSC - 0.5f - sh, 0.1f);
    float bw = rw / 7.0f, bh = rh / 7.0f;
    float bws = bw * 0.25f, bhs = bh * 0.25f;
    int ph = bin / 7, pw = bin - ph * 7;
    float tx = 0.f, ty = 0.f;
    if (has_off) {
        tx = off[n * 98 + bin] * 0.1f;
        ty = off[n * 98 + 49 + bin] * 0.1f;
    }
    float wstart = pw * bw + sw + tx * rw;
    float hstart = ph * bh + sh + ty * rh;
#pragma unroll
    for (int i = 0; i < 16; ++i) g[tid][i] = 0.f;
    int gy0 = 0, gx0 = 0, cnt = 0;
#pragma unroll
    for (int s = 0; s < 16; ++s) {
        float fx = wstart + (s & 3) * bws;
        float fy = hstart + (s >> 2) * bhs;
        bool valid = (fx >= -0.5f) && (fx <= 24.5f) && (fy >= -0.5f) && (fy <= 24.5f);
        float xc = fminf(fmaxf(fx, 0.f), 24.f);
        float yc = fminf(fmaxf(fy, 0.f), 24.f);
        float x0f = floorf(xc), y0f = floorf(yc);
        float dx = xc - x0f, dy = yc - y0f;
        int x0 = (int)x0f, y0 = (int)y0f;
        int x1 = (int)ceilf(xc), y1 = (int)ceilf(yc);
        if (s == 0) { gy0 = y0; gx0 = x0; }
        float w00 = (1.f - dx) * (1.f - dy), w01 = dx * (1.f - dy);
        float w10 = (1.f - dx) * dy,         w11 = dx * dy;
        if (!valid) { w00 = w01 = w10 = w11 = 0.f; }
        cnt += valid ? 1 : 0;
        int ry0 = (y0 - gy0) * 4, ry1 = (y1 - gy0) * 4;
        g[tid][ry0 + (x0 - gx0)] += w00;
        g[tid][ry0 + (x1 - gx0)] += w01;
        g[tid][ry1 + (x0 - gx0)] += w10;
        g[tid][ry1 + (x1 - gx0)] += w11;
    }
    float inv = 1.0f / fmaxf((float)cnt, 1.0f);
    float4* wp = (float4*)(wbuf + (size_t)idx * 16);
#pragma unroll
    for (int q = 0; q < 4; ++q)
        wp[q] = make_float4(g[tid][q * 4] * inv, g[tid][q * 4 + 1] * inv,
                            g[tid][q * 4 + 2] * inv, g[tid][q * 4 + 3] * inv);
    bbuf[idx] = gy0 | (gx0 << 8) | (b << 16);
}

// ---------------- pool gather ----------------------------------------------
__global__ __launch_bounds__(256) void pool_gather(
        const float* __restrict__ feat, const float* __restrict__ wbuf,
        const int* __restrict__ bbuf, unsigned short* __restrict__ P) {
    __shared__ unsigned short sOut[128 * 49];
    int q = blockIdx.x;            // channel half: 0 or 1
    int n = blockIdx.y;            // roi
    int tid = threadIdx.x;
    int wv = tid >> 6, lane = tid & 63;
    int cbase = q * 128 + lane * 2;

    for (int bin = wv; bin < 49; bin += 4) {
        int di = n * 49 + bin;
        int base = bbuf[di];
        int gy0 = base & 255, gx0 = (base >> 8) & 255, b = base >> 16;
        const float4* wp = (const float4*)(wbuf + (size_t)di * 16);
        float4 w0 = wp[0], w1 = wp[1], w2 = wp[2], w3 = wp[3];
        float ww[16] = { w0.x, w0.y, w0.z, w0.w, w1.x, w1.y, w1.z, w1.w,
                         w2.x, w2.y, w2.z, w2.w, w3.x, w3.y, w3.z, w3.w };
        int rowOff[4], colOff[4];
#pragma unroll
        for (int r = 0; r < 4; ++r) {
            rowOff[r] = min(gy0 + r, 24) * 25;
            colOff[r] = min(gx0 + r, 24);
        }
        int b625 = b * 625;
        float ax = 0.f, ay = 0.f;
#pragma unroll
        for (int cell = 0; cell < 16; ++cell) {
            int pix = b625 + rowOff[cell >> 2] + colOff[cell & 3];
            float2 v = *(const float2*)(feat + (size_t)pix * 256 + cbase);
            ax += ww[cell] * v.x;
            ay += ww[cell] * v.y;
        }
        sOut[(lane * 2) * 49 + bin] = f2bf(ax);
        sOut[(lane * 2 + 1) * 49 + bin] = f2bf(ay);
    }
    __syncthreads();
    const uint2* so = (const uint2*)sOut;
    uint2* dp = (uint2*)(P + (size_t)n * INF + q * 128 * 49);
    for (int i = tid; i < 128 * 49 / 4; i += 256) dp[i] = so[i];
}

// ---------------- barrier-free MFMA GEMM (BM=256=M) -> fp32 partials --------
// NT layout: A (bf16, M x K row-major), B (fp32, N x K row-major). Each wave
// owns 64 rows x BN cols. Fragments loaded DIRECTLY from global:
//   A frag i: lane(l16,quad) <- A[wave*64+i*16+l16][kk+quad*8 .. +8]  (16 B)
//   B frag j: lane(l16,quad) <- B[n0+j*16+l16][kk+quad*8 .. +8] (fp32, 32 B)
// No LDS, no __syncthreads -> compiler emits fine-grained vmcnt; manual
// 1-step prefetch overlaps next tile's 8 loads with current 8 MFMAs.
template <int BN>
__global__ __launch_bounds__(256, 2) void gemm_nt_part(
        const unsigned short* __restrict__ A, const float* __restrict__ Bw,
        float* __restrict__ Cpart, int N, int K, int kSteps) {
    constexpr int BM = 256;
    constexpr int FM = 4, FN = BN / 16;
    const int tid = threadIdx.x;
    const int lane = tid & 63;
    const int wave = tid >> 6;
    const int n0 = blockIdx.x * BN;
    const int k0 = blockIdx.z * kSteps * 32;
    const int quad = lane >> 4;
    const int l16 = lane & 15;

    floatx4 acc[FM][FN];
#pragma unroll
    for (int i = 0; i < FM; ++i)
#pragma unroll
        for (int j = 0; j < FN; ++j) acc[i][j] = (floatx4)0.f;

    const unsigned short* ap[FM];
#pragma unroll
    for (int i = 0; i < FM; ++i)
        ap[i] = A + (size_t)(wave * 64 + i * 16 + l16) * K + k0 + quad * 8;
    const float* bp[FN];
#pragma unroll
    for (int j = 0; j < FN; ++j)
        bp[j] = Bw + (size_t)(n0 + j * 16 + l16) * K + k0 + quad * 8;

    short8 an[FM];
    float4 bn0[FN], bn1[FN];
#pragma unroll
    for (int i = 0; i < FM; ++i) an[i] = *(const short8*)ap[i];
#pragma unroll
    for (int j = 0; j < FN; ++j) {
        bn0[j] = *(const float4*)bp[j];
        bn1[j] = *(const float4*)(bp[j] + 4);
    }

    for (int ks = 0; ks < kSteps; ++ks) {
        short8 a[FM];
        float4 b0[FN], b1[FN];
#pragma unroll
        for (int i = 0; i < FM; ++i) a[i] = an[i];
#pragma unroll
        for (int j = 0; j < FN; ++j) { b0[j] = bn0[j]; b1[j] = bn1[j]; }
        if (ks + 1 < kSteps) {      // prefetch next k-tile (overlaps MFMAs)
#pragma unroll
            for (int i = 0; i < FM; ++i) {
                ap[i] += 32;
                an[i] = *(const short8*)ap[i];
            }
#pragma unroll
            for (int j = 0; j < FN; ++j) {
                bp[j] += 32;
                bn0[j] = *(const float4*)bp[j];
                bn1[j] = *(const float4*)(bp[j] + 4);
            }
        }
#pragma unroll
        for (int j = 0; j < FN; ++j) {
            short8 bf;
            bf[0] = (short)f2bf(b0[j].x); bf[1] = (short)f2bf(b0[j].y);
            bf[2] = (short)f2bf(b0[j].z); bf[3] = (short)f2bf(b0[j].w);
            bf[4] = (short)f2bf(b1[j].x); bf[5] = (short)f2bf(b1[j].y);
            bf[6] = (short)f2bf(b1[j].z); bf[7] = (short)f2bf(b1[j].w);
#pragma unroll
            for (int i = 0; i < FM; ++i)
                acc[i][j] = __builtin_amdgcn_mfma_f32_16x16x32_bf16(a[i], bf, acc[i][j], 0, 0, 0);
        }
    }
    // epilogue: full contiguous row spans (complete cache lines)
    float* Cp = Cpart + (size_t)blockIdx.z * BM * N;
#pragma unroll
    for (int i = 0; i < FM; ++i)
#pragma unroll
        for (int rr = 0; rr < 4; ++rr) {
            int row = wave * 64 + i * 16 + quad * 4 + rr;
            float* cr = Cp + (size_t)row * N + n0;
#pragma unroll
            for (int j = 0; j < FN; ++j)
                cr[j * 16 + l16] = acc[i][j][rr];
        }
}

// ---------------- reduce over Z + bias + optional relu + casts --------------
__global__ __launch_bounds__(256) void reduce_bias(
        const float* __restrict__ part, int zc, int mn4,
        const float* __restrict__ bias, int nmask, int relu,
        unsigned short* __restrict__ obf, float* __restrict__ of) {
    int idx = blockIdx.x * 256 + threadIdx.x;    // float4 index
    if (idx >= mn4) return;
    int idx4 = idx * 4;
    const float* bp = bias + (idx4 & nmask);
    float4 acc = *(const float4*)bp;
    const float4* p = (const float4*)part + idx;
    for (int z = 0; z < zc; ++z) {
        float4 v = p[(size_t)z * mn4];
        acc.x += v.x; acc.y += v.y; acc.z += v.z; acc.w += v.w;
    }
    if (relu) {
        acc.x = fmaxf(acc.x, 0.f); acc.y = fmaxf(acc.y, 0.f);
        acc.z = fmaxf(acc.z, 0.f); acc.w = fmaxf(acc.w, 0.f);
    }
    if (obf) {
        ushort4 h;
        h.x = f2bf(acc.x); h.y = f2bf(acc.y); h.z = f2bf(acc.z); h.w = f2bf(acc.w);
        *(ushort4*)(obf + idx4) = h;
    }
    if (of) *(float4*)(of + idx4) = acc;
}

// ---------------- G3: off = relu(h2) @ w3^T + b3  (256 x 98) ----------------
__global__ __launch_bounds__(128) void fc_small(
        const float* __restrict__ h2, const float* __restrict__ w3,
        const float* __restrict__ b3, float* __restrict__ out) {
    __shared__ float shl[1024];
    int n = blockIdx.x, tid = threadIdx.x;
    for (int i = tid; i < 1024; i += 128) shl[i] = fmaxf(h2[(size_t)n * 1024 + i], 0.f);
    __syncthreads();
    if (tid < 98) {
        float acc = b3[tid];
        const float* w = w3 + (size_t)tid * 1024;
        for (int k = 0; k < 1024; k += 4) {
            float4 wv = *(const float4*)(w + k);
            acc += shl[k] * wv.x + shl[k + 1] * wv.y + shl[k + 2] * wv.z + shl[k + 3] * wv.w;
        }
        out[n * 98 + tid] = acc;
    }
}

// ---------------- G6: out = relu(h4) @ box_w^T + box_b  (256 x 4) -----------
__global__ __launch_bounds__(64) void head_kernel(
        const float* __restrict__ h4, const float* __restrict__ bw,
        const float* __restrict__ bb, float* __restrict__ out) {
    int n = blockIdx.x, t = threadIdx.x;
    float a0 = 0, a1 = 0, a2 = 0, a3 = 0;
    for (int k = t; k < 512; k += 64) {
        float v = fmaxf(h4[(size_t)n * 512 + k], 0.f);
        a0 += v * bw[k]; a1 += v * bw[512 + k];
        a2 += v * bw[1024 + k]; a3 += v * bw[1536 + k];
    }
#pragma unroll
    for (int o = 32; o > 0; o >>= 1) {
        a0 += __shfl_down(a0, o); a1 += __shfl_down(a1, o);
        a2 += __shfl_down(a2, o); a3 += __shfl_down(a3, o);
    }
    if (t == 0) {
        out[n * 4 + 0] = a0 + bb[0]; out[n * 4 + 1] = a1 + bb[1];
        out[n * 4 + 2] = a2 + bb[2]; out[n * 4 + 3] = a3 + bb[3];
    }
}

// ---------------------------------------------------------------------------
extern "C" void kernel_launch(void* const* d_in, const int* in_sizes, int n_in,
                              void* d_out, int out_size, void* d_ws, size_t ws_size,
                              hipStream_t stream) {
    const float* x      = (const float*)d_in[0];
    const float* rois   = (const float*)d_in[1];
    const float* off_w1 = (const float*)d_in[2];
    const float* off_b1 = (const float*)d_in[3];
    const float* off_w2 = (const float*)d_in[4];
    const float* off_b2 = (const float*)d_in[5];
    const float* off_w3 = (const float*)d_in[6];
    const float* off_b3 = (const float*)d_in[7];
    const float* fc1_w  = (const float*)d_in[8];
    const float* fc1_b  = (const float*)d_in[9];
    const float* fc2_w  = (const float*)d_in[10];
    const float* fc2_b  = (const float*)d_in[11];
    const float* box_w  = (const float*)d_in[12];
    const float* box_b  = (const float*)d_in[13];
    float* out = (float*)d_out;

    char* ws = (char*)d_ws;
    size_t o = 0;
    auto carve = [&](size_t bytes) { char* p = ws + o; o += (bytes + 255) & ~(size_t)255; return p; };
    float*          xT   = (float*)carve((size_t)NB * 625 * 256 * 4);   // 5.12 MB
    unsigned short* P    = (unsigned short*)carve((size_t)NROI * INF * 2); // shared p0/p1
    unsigned short* h1b  = (unsigned short*)carve((size_t)NROI * DFC * 2);
    float*          h2   = (float*)carve((size_t)NROI * DFC * 4);
    float*          offb = (float*)carve((size_t)NROI * 98 * 4);
    unsigned short* h3b  = (unsigned short*)carve((size_t)NROI * FCC * 2);
    float*          h4   = (float*)carve((size_t)NROI * FCC * 4);
    float*          wbuf = (float*)carve((size_t)NROI * 49 * 16 * 4);   // 803 KB
    int*            bbuf = (int*)carve((size_t)NROI * 49 * 4);
    size_t fixed = o;
    const size_t SLAB = (size_t)NROI * DFC * 4;   // 1 MB (G1/G2-sized slice)
    int zg1;                        // tier on ws_size (constant -> graph-safe)
    if      (ws_size >= fixed + 28 * SLAB) zg1 = 28;
    else if (ws_size >= fixed + 14 * SLAB) zg1 = 14;
    else                                   zg1 = 7;
    int zg2 = (zg1 >= 8) ? 8 : 4;   // divides 32 (G2) and 16 (G5)
    float* part = (float*)carve((size_t)zg1 * SLAB);

    // 1. channels-last transpose of x
    transpose_kernel<<<dim3(20, 8, 8), 256, 0, stream>>>(x, xT);
    // 2. pool pass 0 (zero offsets)
    pool_prep<<<49, 256, 0, stream>>>(rois, nullptr, 0, wbuf, bbuf);
    pool_gather<<<dim3(2, NROI), 256, 0, stream>>>(xT, wbuf, bbuf, P);
    // 3. G1 partials + reduce(+b1+relu) -> h1b     (256x12544x1024)
    gemm_nt_part<32><<<dim3(32, 1, zg1), 256, 0, stream>>>(P, off_w1, part, DFC, INF, 392 / zg1);
    reduce_bias<<<256, 256, 0, stream>>>(part, zg1, NROI * DFC / 4, off_b1, DFC - 1, 1, h1b, nullptr);
    // 4. G2 partials + reduce(+b2) -> h2 (fp32; fc_small applies relu)
    gemm_nt_part<32><<<dim3(32, 1, zg2), 256, 0, stream>>>(h1b, off_w2, part, DFC, DFC, 32 / zg2);
    reduce_bias<<<256, 256, 0, stream>>>(part, zg2, NROI * DFC / 4, off_b2, DFC - 1, 0, nullptr, h2);
    // 5. G3: offb = relu(h2) @ w3^T + b3
    fc_small<<<NROI, 128, 0, stream>>>(h2, off_w3, off_b3, offb);
    // 6. pool pass 1 (learned offsets), reuses P
    pool_prep<<<49, 256, 0, stream>>>(rois, offb, 1, wbuf, bbuf);
    pool_gather<<<dim3(2, NROI), 256, 0, stream>>>(xT, wbuf, bbuf, P);
    // 7. G4 partials + reduce(+fc1_b+relu) -> h3b  (256x12544x512)
    gemm_nt_part<32><<<dim3(16, 1, zg1), 256, 0, stream>>>(P, fc1_w, part, FCC, INF, 392 / zg1);
    reduce_bias<<<128, 256, 0, stream>>>(part, zg1, NROI * FCC / 4, fc1_b, FCC - 1, 1, h3b, nullptr);
    // 8. G5 partials + reduce(+fc2_b) -> h4 (fp32; head applies relu)
    gemm_nt_part<32><<<dim3(16, 1, zg2), 256, 0, stream>>>(h3b, fc2_w, part, FCC, FCC, 16 / zg2);
    reduce_bias<<<128, 256, 0, stream>>>(part, zg2, NROI * FCC / 4, fc2_b, FCC - 1, 0, nullptr, h4);
    // 9. G6: out = relu(h4) @ box_w^T + box_b
    head_kernel<<<NROI, 64, 0, stream>>>(h4, box_w, box_b, out);
}

// Round 8
// 302.742 us; speedup vs baseline: 1.1182x; 1.1182x over previous
//
#include <hip/hip_runtime.h>
#include <hip/hip_bf16.h>

// ---------------------------------------------------------------------------
// FCx2DetHead pipeline. R8: restructured GEMM K-loop (the m97-plateau fix).
//  - 3-slot LDS circular pipeline, ALL staging via global_load_lds (zero
//    VGPR; R5/R7 showed the compiler cannot hold register prefetch).
//  - Inline-asm `s_waitcnt vmcnt(5)` + raw `s_barrier` instead of
//    __syncthreads: loads stay outstanding across the barrier, each tile has
//    ~2 steps (~1300 cyc) to land -> no per-step vmcnt(0) drain.
//  - B fp32 staged raw (16B-unit XOR swizzle), f2bf at consume.
//  - pool_prep fused into pool_gather; fc_small does 2 rois/block.
// ---------------------------------------------------------------------------

#define NROI 256
#define NB   8
#define INF  12544   // 256*49
#define DFC  1024
#define FCC  512

typedef __attribute__((ext_vector_type(8))) short short8;
typedef __attribute__((ext_vector_type(4))) float floatx4;

static __device__ __forceinline__ unsigned short f2bf(float f) {
    unsigned int u = __float_as_uint(f);
    unsigned int r = (u + 0x7fffu + ((u >> 16) & 1u)) >> 16;
    return (unsigned short)r;
}

static __device__ __forceinline__ void async_copy16(const void* g, void* l) {
    __builtin_amdgcn_global_load_lds(
        (const __attribute__((address_space(1))) unsigned int*)g,
        (__attribute__((address_space(3))) unsigned int*)l, 16, 0, 0);
}

// ---------------- transpose x (B,C,H,W) -> feat (B,H,W,C) -------------------
__global__ __launch_bounds__(256) void transpose_kernel(
        const float* __restrict__ x, float* __restrict__ xT) {
    __shared__ float t[32][33];
    int b  = blockIdx.z;
    int cb = blockIdx.y * 32;     // channel tile
    int lb = blockIdx.x * 32;     // hw tile (0..624)
    int tx = threadIdx.x & 31, ty = threadIdx.x >> 5;
#pragma unroll
    for (int r = 0; r < 4; ++r) {
        int c = cb + ty + r * 8, l = lb + tx;
        if (l < 625) t[ty + r * 8][tx] = x[(size_t)(b * 256 + c) * 625 + l];
    }
    __syncthreads();
#pragma unroll
    for (int r = 0; r < 4; ++r) {
        int l = lb + ty + r * 8, c = cb + tx;
        if (l < 625) xT[((size_t)b * 625 + l) * 256 + c] = t[tx][ty + r * 8];
    }
}

// ---------------- fused deformable RoI pool (prep + gather) -----------------
// grid (2 channel-halves, 256 rois) x 256 threads. Phase 1: threads 0..48
// collapse their bin's 16 samples x 4 bilinear taps into a 4x4 pixel grid
// (1/cnt folded) in LDS. Phase 2: wave wv gathers bins wv, wv+4, ...;
// lane handles 2 channels (float2), 16 unconditional clamped loads per bin.
__global__ __launch_bounds__(256) void pool_kernel(
        const float* __restrict__ feat, const float* __restrict__ rois,
        const float* __restrict__ off, int has_off,
        unsigned short* __restrict__ P) {
    __shared__ float sGrid[49][16];
    __shared__ int   sBase[49];
    __shared__ unsigned short sOut[128 * 49];
    const float SSC = (float)(25.0 / 255.0);
    int q = blockIdx.x;            // channel half
    int n = blockIdx.y;            // roi
    int tid = threadIdx.x;

    if (tid < 49) {
        int bin = tid;
        const float* r = rois + n * 5;
        int b = (int)r[0];
        float sw = rintf(r[1]) * SSC - 0.5f;
        float sh = rintf(r[2]) * SSC - 0.5f;
        float rw = fmaxf((rintf(r[3]) + 1.0f) * SSC - 0.5f - sw, 0.1f);
        float rh = fmaxf((rintf(r[4]) + 1.0f) * SSC - 0.5f - sh, 0.1f);
        float bw = rw / 7.0f, bh = rh / 7.0f;
        float bws = bw * 0.25f, bhs = bh * 0.25f;
        int ph = bin / 7, pw = bin - ph * 7;
        float tx = 0.f, ty = 0.f;
        if (has_off) {
            tx = off[n * 98 + bin] * 0.1f;
            ty = off[n * 98 + 49 + bin] * 0.1f;
        }
        float wstart = pw * bw + sw + tx * rw;
        float hstart = ph * bh + sh + ty * rh;
#pragma unroll
        for (int i = 0; i < 16; ++i) sGrid[bin][i] = 0.f;
        int gy0 = 0, gx0 = 0, cnt = 0;
#pragma unroll
        for (int s = 0; s < 16; ++s) {
            float fx = wstart + (s & 3) * bws;
            float fy = hstart + (s >> 2) * bhs;
            bool valid = (fx >= -0.5f) && (fx <= 24.5f) && (fy >= -0.5f) && (fy <= 24.5f);
            float xc = fminf(fmaxf(fx, 0.f), 24.f);
            float yc = fminf(fmaxf(fy, 0.f), 24.f);
            float x0f = floorf(xc), y0f = floorf(yc);
            float dx = xc - x0f, dy = yc - y0f;
            int x0 = (int)x0f, y0 = (int)y0f;
            int x1 = (int)ceilf(xc), y1 = (int)ceilf(yc);
            if (s == 0) { gy0 = y0; gx0 = x0; }
            float w00 = (1.f - dx) * (1.f - dy), w01 = dx * (1.f - dy);
            float w10 = (1.f - dx) * dy,         w11 = dx * dy;
            if (!valid) { w00 = w01 = w10 = w11 = 0.f; }
            cnt += valid ? 1 : 0;
            int ry0 = (y0 - gy0) * 4, ry1 = (y1 - gy0) * 4;
            sGrid[bin][ry0 + (x0 - gx0)] += w00;
            sGrid[bin][ry0 + (x1 - gx0)] += w01;
            sGrid[bin][ry1 + (x0 - gx0)] += w10;
            sGrid[bin][ry1 + (x1 - gx0)] += w11;
        }
        float inv = 1.0f / fmaxf((float)cnt, 1.0f);
#pragma unroll
        for (int i = 0; i < 16; ++i) sGrid[bin][i] *= inv;
        sBase[bin] = gy0 | (gx0 << 8) | (b << 16);
    }
    __syncthreads();

    int wv = tid >> 6, lane = tid & 63;
    int cbase = q * 128 + lane * 2;
    for (int bin = wv; bin < 49; bin += 4) {
        int base = sBase[bin];
        int gy0 = base & 255, gx0 = (base >> 8) & 255, b = base >> 16;
        const float4* wp = (const float4*)sGrid[bin];
        float4 w0 = wp[0], w1 = wp[1], w2 = wp[2], w3 = wp[3];
        float ww[16] = { w0.x, w0.y, w0.z, w0.w, w1.x, w1.y, w1.z, w1.w,
                         w2.x, w2.y, w2.z, w2.w, w3.x, w3.y, w3.z, w3.w };
        int rowOff[4], colOff[4];
#pragma unroll
        for (int r = 0; r < 4; ++r) {
            rowOff[r] = min(gy0 + r, 24) * 25;
            colOff[r] = min(gx0 + r, 24);
        }
        int b625 = b * 625;
        float ax = 0.f, ay = 0.f;
#pragma unroll
        for (int cell = 0; cell < 16; ++cell) {
            int pix = b625 + rowOff[cell >> 2] + colOff[cell & 3];
            float2 v = *(const float2*)(feat + (size_t)pix * 256 + cbase);
            ax += ww[cell] * v.x;
            ay += ww[cell] * v.y;
        }
        sOut[(lane * 2) * 49 + bin] = f2bf(ax);
        sOut[(lane * 2 + 1) * 49 + bin] = f2bf(ay);
    }
    __syncthreads();
    const uint2* so = (const uint2*)sOut;
    uint2* dp = (uint2*)(P + (size_t)n * INF + q * 128 * 49);
    for (int i = tid; i < 128 * 49 / 4; i += 256) dp[i] = so[i];
}

// ---------------- pipelined MFMA GEMM (BM=256=M, BN=32) -> fp32 partials ----
// 3-slot LDS circular buffer; ALL staging via global_load_lds (5 issues per
// thread per k-step: 4x A(16B bf16), 1x B(16B fp32)). Synchronization by
// inline-asm `s_waitcnt vmcnt(5)` + raw `s_barrier` so 2 slots of loads stay
// outstanding across the barrier (no compiler vmcnt(0) drain).
// A swizzle: 16B-unit kg4 ^= (row>>1)&3 (2-way LDS conflicts = free).
// B swizzle: 16B-unit kg  ^= (row>>1)&7 (2-way, f2bf at consume).
__global__ __launch_bounds__(256) void gemm_pipe(
        const unsigned short* __restrict__ A, const float* __restrict__ Bw,
        float* __restrict__ Cpart, int N, int K, int kSteps) {
    constexpr int BM = 256, BN = 32, D = 3;
    constexpr int FM = 4, FN = 2;
    __shared__ unsigned short As[D][BM * 32];  // 16 KB / slot
    __shared__ float          Bs[D][BN * 32];  //  4 KB / slot
    const int tid = threadIdx.x;
    const int lane = tid & 63;
    const int wave = tid >> 6;
    const int n0 = blockIdx.x * BN;
    const int k0 = blockIdx.z * kSteps * 32;
    const int quad = lane >> 4;
    const int l16 = lane & 15;

    floatx4 acc[FM][FN];
#pragma unroll
    for (int i = 0; i < FM; ++i)
#pragma unroll
        for (int j = 0; j < FN; ++j) acc[i][j] = (floatx4)0.f;

    // A staging: thread t, copy i -> LDS 16B-unit (i*256 + t)
    const unsigned short* ag[4];
    int albase[4];
#pragma unroll
    for (int i = 0; i < 4; ++i) {
        int idx = tid + i * 256;
        int row = idx >> 2;
        int kg4 = (idx & 3) ^ ((row >> 1) & 3);
        ag[i] = A + (size_t)row * K + kg4 * 8;
        albase[i] = (i * 256 + wave * 64) * 16;   // wave-uniform byte base
    }
    // B staging: thread t -> LDS 16B-unit t
    const int brow = tid >> 3;
    const int bkg = (tid & 7) ^ ((brow >> 1) & 7);
    const float* bg = Bw + (size_t)(n0 + brow) * K + bkg * 4;
    const int blbase = wave * 64 * 16;

    auto issue = [&](int slot, int kk) {
#pragma unroll
        for (int i = 0; i < 4; ++i)
            async_copy16(ag[i] + kk, (char*)&As[slot][0] + albase[i]);
        async_copy16(bg + kk, (char*)&Bs[slot][0] + blbase);
    };

    // prologue: slots 0..D-2
#pragma unroll
    for (int p = 0; p < D - 1; ++p) {
        int pk = (p < kSteps) ? p : (kSteps - 1);
        issue(p, k0 + pk * 32);
    }

    int cur = 0;
    for (int ks = 0; ks < kSteps; ++ks) {
        // wait own slot-cur loads (2 slots = 10... D=3: 1 slot of 5 behind)
        asm volatile("s_waitcnt vmcnt(5)" ::: "memory");
        asm volatile("s_barrier" ::: "memory");
        // issue slot ks+D-1 (clamped k keeps the vmcnt invariant constant)
        int pfs = cur + D - 1; if (pfs >= D) pfs -= D;
        int pfk = ks + D - 1; if (pfk >= kSteps) pfk = kSteps - 1;
        issue(pfs, k0 + pfk * 32);
        // fragments from slot cur
        short8 a[FM], bf[FN];
#pragma unroll
        for (int i = 0; i < FM; ++i) {
            int r = wave * 64 + i * 16 + l16;
            int sl = quad ^ ((r >> 1) & 3);
            a[i] = *(const short8*)(&As[cur][0] + r * 32 + sl * 8);
        }
#pragma unroll
        for (int j = 0; j < FN; ++j) {
            int r = j * 16 + l16;
            int sw8 = (r >> 1) & 7;
            int g0 = (quad * 2) ^ sw8;
            int g1 = (quad * 2 + 1) ^ sw8;
            float4 v0 = *(const float4*)(&Bs[cur][0] + r * 32 + g0 * 4);
            float4 v1 = *(const float4*)(&Bs[cur][0] + r * 32 + g1 * 4);
            bf[j][0] = (short)f2bf(v0.x); bf[j][1] = (short)f2bf(v0.y);
            bf[j][2] = (short)f2bf(v0.z); bf[j][3] = (short)f2bf(v0.w);
            bf[j][4] = (short)f2bf(v1.x); bf[j][5] = (short)f2bf(v1.y);
            bf[j][6] = (short)f2bf(v1.z); bf[j][7] = (short)f2bf(v1.w);
        }
#pragma unroll
        for (int i = 0; i < FM; ++i)
#pragma unroll
            for (int j = 0; j < FN; ++j)
                acc[i][j] = __builtin_amdgcn_mfma_f32_16x16x32_bf16(a[i], bf[j], acc[i][j], 0, 0, 0);
        cur = cur + 1; if (cur >= D) cur = 0;
    }
    // epilogue: full contiguous row spans (complete cache lines)
    float* Cp = Cpart + (size_t)blockIdx.z * BM * N;
#pragma unroll
    for (int i = 0; i < FM; ++i)
#pragma unroll
        for (int rr = 0; rr < 4; ++rr) {
            int row = wave * 64 + i * 16 + quad * 4 + rr;
            float* cr = Cp + (size_t)row * N + n0;
#pragma unroll
            for (int j = 0; j < FN; ++j)
                cr[j * 16 + l16] = acc[i][j][rr];
        }
}

// ---------------- reduce over Z + bias + optional relu + casts --------------
__global__ __launch_bounds__(256) void reduce_bias(
        const float* __restrict__ part, int zc, int mn4,
        const float* __restrict__ bias, int nmask, int relu,
        unsigned short* __restrict__ obf, float* __restrict__ of) {
    int idx = blockIdx.x * 256 + threadIdx.x;    // float4 index
    if (idx >= mn4) return;
    int idx4 = idx * 4;
    const float* bp = bias + (idx4 & nmask);
    float4 acc = *(const float4*)bp;
    const float4* p = (const float4*)part + idx;
    for (int z = 0; z < zc; ++z) {
        float4 v = p[(size_t)z * mn4];
        acc.x += v.x; acc.y += v.y; acc.z += v.z; acc.w += v.w;
    }
    if (relu) {
        acc.x = fmaxf(acc.x, 0.f); acc.y = fmaxf(acc.y, 0.f);
        acc.z = fmaxf(acc.z, 0.f); acc.w = fmaxf(acc.w, 0.f);
    }
    if (obf) {
        ushort4 h;
        h.x = f2bf(acc.x); h.y = f2bf(acc.y); h.z = f2bf(acc.z); h.w = f2bf(acc.w);
        *(ushort4*)(obf + idx4) = h;
    }
    if (of) *(float4*)(of + idx4) = acc;
}

// ---------------- G3: off = relu(h2) @ w3^T + b3  (2 rois / block) ----------
__global__ __launch_bounds__(256) void fc_small(
        const float* __restrict__ h2, const float* __restrict__ w3,
        const float* __restrict__ b3, float* __restrict__ out) {
    __shared__ float shl[2][1024];
    int n2 = blockIdx.x * 2;
    int tid = threadIdx.x;
    for (int i = tid; i < 2048; i += 256)
        shl[i >> 10][i & 1023] = fmaxf(h2[(size_t)n2 * 1024 + i], 0.f);
    __syncthreads();
    int h = tid >> 7, o = tid & 127;
    if (o < 98) {
        float acc = b3[o];
        const float* w = w3 + (size_t)o * 1024;
        const float* s = shl[h];
        for (int k = 0; k < 1024; k += 4) {
            float4 wv = *(const float4*)(w + k);
            acc += s[k] * wv.x + s[k + 1] * wv.y + s[k + 2] * wv.z + s[k + 3] * wv.w;
        }
        out[(n2 + h) * 98 + o] = acc;
    }
}

// ---------------- G6: out = relu(h4) @ box_w^T + box_b  (256 x 4) -----------
__global__ __launch_bounds__(64) void head_kernel(
        const float* __restrict__ h4, const float* __restrict__ bw,
        const float* __restrict__ bb, float* __restrict__ out) {
    int n = blockIdx.x, t = threadIdx.x;
    float a0 = 0, a1 = 0, a2 = 0, a3 = 0;
    for (int k = t; k < 512; k += 64) {
        float v = fmaxf(h4[(size_t)n * 512 + k], 0.f);
        a0 += v * bw[k]; a1 += v * bw[512 + k];
        a2 += v * bw[1024 + k]; a3 += v * bw[1536 + k];
    }
#pragma unroll
    for (int o = 32; o > 0; o >>= 1) {
        a0 += __shfl_down(a0, o); a1 += __shfl_down(a1, o);
        a2 += __shfl_down(a2, o); a3 += __shfl_down(a3, o);
    }
    if (t == 0) {
        out[n * 4 + 0] = a0 + bb[0]; out[n * 4 + 1] = a1 + bb[1];
        out[n * 4 + 2] = a2 + bb[2]; out[n * 4 + 3] = a3 + bb[3];
    }
}

// ---------------------------------------------------------------------------
extern "C" void kernel_launch(void* const* d_in, const int* in_sizes, int n_in,
                              void* d_out, int out_size, void* d_ws, size_t ws_size,
                              hipStream_t stream) {
    const float* x      = (const float*)d_in[0];
    const float* rois   = (const float*)d_in[1];
    const float* off_w1 = (const float*)d_in[2];
    const float* off_b1 = (const float*)d_in[3];
    const float* off_w2 = (const float*)d_in[4];
    const float* off_b2 = (const float*)d_in[5];
    const float* off_w3 = (const float*)d_in[6];
    const float* off_b3 = (const float*)d_in[7];
    const float* fc1_w  = (const float*)d_in[8];
    const float* fc1_b  = (const float*)d_in[9];
    const float* fc2_w  = (const float*)d_in[10];
    const float* fc2_b  = (const float*)d_in[11];
    const float* box_w  = (const float*)d_in[12];
    const float* box_b  = (const float*)d_in[13];
    float* out = (float*)d_out;

    char* ws = (char*)d_ws;
    size_t o = 0;
    auto carve = [&](size_t bytes) { char* p = ws + o; o += (bytes + 255) & ~(size_t)255; return p; };
    float*          xT   = (float*)carve((size_t)NB * 625 * 256 * 4);   // 5.12 MB
    unsigned short* P    = (unsigned short*)carve((size_t)NROI * INF * 2); // shared p0/p1
    unsigned short* h1b  = (unsigned short*)carve((size_t)NROI * DFC * 2);
    float*          h2   = (float*)carve((size_t)NROI * DFC * 4);
    float*          offb = (float*)carve((size_t)NROI * 98 * 4);
    unsigned short* h3b  = (unsigned short*)carve((size_t)NROI * FCC * 2);
    float*          h4   = (float*)carve((size_t)NROI * FCC * 4);
    size_t fixed = o;
    const size_t SLAB = (size_t)NROI * DFC * 4;   // 1 MB (G1/G2-sized slice)
    int zg1;                        // tier on ws_size (constant -> graph-safe)
    if      (ws_size >= fixed + 28 * SLAB) zg1 = 28;
    else if (ws_size >= fixed + 14 * SLAB) zg1 = 14;
    else                                   zg1 = 7;
    float* part = (float*)carve((size_t)zg1 * SLAB);

    // 1. channels-last transpose of x
    transpose_kernel<<<dim3(20, 8, 8), 256, 0, stream>>>(x, xT);
    // 2. pool pass 0 (zero offsets), prep fused
    pool_kernel<<<dim3(2, NROI), 256, 0, stream>>>(xT, rois, nullptr, 0, P);
    // 3. G1 partials + reduce(+b1+relu) -> h1b     (256x12544x1024)
    gemm_pipe<<<dim3(32, 1, zg1), 256, 0, stream>>>(P, off_w1, part, DFC, INF, 392 / zg1);
    reduce_bias<<<256, 256, 0, stream>>>(part, zg1, NROI * DFC / 4, off_b1, DFC - 1, 1, h1b, nullptr);
    // 4. G2 partials + reduce(+b2) -> h2 (fp32; fc_small applies relu)
    gemm_pipe<<<dim3(32, 1, 8), 256, 0, stream>>>(h1b, off_w2, part, DFC, DFC, 4);
    reduce_bias<<<256, 256, 0, stream>>>(part, 8, NROI * DFC / 4, off_b2, DFC - 1, 0, nullptr, h2);
    // 5. G3: offb = relu(h2) @ w3^T + b3
    fc_small<<<128, 256, 0, stream>>>(h2, off_w3, off_b3, offb);
    // 6. pool pass 1 (learned offsets), reuses P
    pool_kernel<<<dim3(2, NROI), 256, 0, stream>>>(xT, rois, offb, 1, P);
    // 7. G4 partials + reduce(+fc1_b+relu) -> h3b  (256x12544x512)
    gemm_pipe<<<dim3(16, 1, zg1), 256, 0, stream>>>(P, fc1_w, part, FCC, INF, 392 / zg1);
    reduce_bias<<<128, 256, 0, stream>>>(part, zg1, NROI * FCC / 4, fc1_b, FCC - 1, 1, h3b, nullptr);
    // 8. G5 partials + reduce(+fc2_b) -> h4 (fp32; head applies relu)
    gemm_pipe<<<dim3(16, 1, 8), 256, 0, stream>>>(h3b, fc2_w, part, FCC, FCC, 2);
    reduce_bias<<<128, 256, 0, stream>>>(part, 8, NROI * FCC / 4, fc2_b, FCC - 1, 0, nullptr, h4);
    // 9. G6: out = relu(h4) @ box_w^T + box_b
    head_kernel<<<NROI, 64, 0, stream>>>(h4, box_w, box_b, out);
}